// Round 13
// baseline (388.450 us; speedup 1.0000x reference)
//
#include <hip/hip_runtime.h>
#include <cstdint>
#include <cstddef>

// DeformablePoseViT: bs=16, lq=1000, d=256, nh=8, L=4, P=4, dh=32
// value pyramid: (80,80),(40,40),(20,20),(10,10) -> lv=8500
//
// Pipeline (R9 structure; value GEMM replaced by register-pipelined v4):
//  0) wconv : Wt_* = bf16(W_*^T) [N][256]
//  1) gemm_v4            : vbf = bf16(value @ W_val + b_val) [136000x256]
//  2) gemm_p2<4,16,false>: Lgo = query @ W_off + b_off       [16000x256]
//  3) gemm_p2<4,8,false> : Lga = query @ W_attn + b_attn     [16000x128]
//  4) sample_fused : XCD batch affinity + LDS precompute + gather
//  5) gemm_p2<4,16,false>: d_out = outs @ W_out + b_out      [16000x256]
//
// gemm_v4: persistent (256 blocks x 512 thr = 8 waves x 16 rows), B 128KB
// LDS-resident (col-permuted + XOR-swizzled). A streams global->VGPR with a
// ROLLING 3-K-step register window (a[8][2] fully unrolled + an[3][2] for
// next tile; all indices static). No inline-asm vmcnt: compiler emits
// precise waits for register loads. ~750cy lookahead ~ HBM latency.

typedef unsigned short u16;
typedef u16 u16x8 __attribute__((ext_vector_type(8)));
typedef __bf16 bf16x8 __attribute__((ext_vector_type(8)));
typedef float f32x4 __attribute__((ext_vector_type(4)));

__device__ inline u16 f2bf(float f) {
  return __builtin_bit_cast(u16, (__bf16)f);
}

__device__ __forceinline__ void glds16(const void* g, void* l) {
  __builtin_amdgcn_global_load_lds(
      (const __attribute__((address_space(1))) void*)g,
      (__attribute__((address_space(3))) void*)l, 16, 0, 0);
}

// ---------------------------------------------------------------------------
// Weight prep: Wt[n][k] = bf16(W[k][n]). K=256 for all 4 matrices.
__global__ __launch_bounds__(256) void wconv(
    const float* __restrict__ W0, const float* __restrict__ W1,
    const float* __restrict__ W2, const float* __restrict__ W3,
    u16* __restrict__ T0, u16* __restrict__ T1, u16* __restrict__ T2,
    u16* __restrict__ T3) {
  __shared__ u16 tile[64][65];
  const float* Ws[4] = {W0, W1, W2, W3};
  u16* Ts[4] = {T0, T1, T2, T3};
  const int Ns[4] = {256, 256, 128, 256};
  const int z = blockIdx.z;
  const int N = Ns[z];
  const int n0 = blockIdx.x * 64;
  if (n0 >= N) return;
  const int k0 = blockIdx.y * 64;
  const float* W = Ws[z];
  u16* Wt = Ts[z];
  const int tr = threadIdx.x >> 6;   // 0..3
  const int tc = threadIdx.x & 63;
#pragma unroll
  for (int r = 0; r < 64; r += 4)
    tile[r + tr][tc] = f2bf(W[(size_t)(k0 + r + tr) * N + n0 + tc]);
  __syncthreads();
#pragma unroll
  for (int r = 0; r < 64; r += 4)
    Wt[(size_t)(n0 + r + tr) * 256 + k0 + tc] = tile[tc][r + tr];
}

// ---------------------------------------------------------------------------
// gemm_v4: vbf = bf16(A[M,256] @ Wt[256,256]^T + bias). See header comment.
__global__ __launch_bounds__(512, 1) void gemm_v4(
    const float* __restrict__ A, const u16* __restrict__ Wt,
    const float* __restrict__ bias, u16* __restrict__ Cv,
    int M, int NT, int G) {
  __shared__ __align__(16) u16 Bls[256 * 256];  // 128 KB
  const int wave = threadIdx.x >> 6;
  const int lane = threadIdx.x & 63;
  const int lr = lane & 15;
  const int lj = lane >> 4;

  // ---- B preload (once per block): 128 insts of 1KB (2 permuted cols) ----
#pragma unroll
  for (int g = 0; g < 16; ++g) {
    int inst = wave * 16 + g;
    int s2 = inst * 2 + (lane >> 5);
    int pc = lane & 31;
    int jc = pc ^ (s2 & 7);
    int c = (s2 & 15) * 16 + (s2 >> 4);  // original column for slot s2
    glds16((const char*)Wt + (size_t)c * 512 + (size_t)jc * 16,
           (char*)Bls + inst * 1024);
  }

  float bv[16];
#pragma unroll
  for (int ni = 0; ni < 16; ++ni) bv[ni] = bias[lr * 16 + ni];

  // rolling A window: K-steps of this tile (a) + first 3 of next tile (an)
  f32x4 a[8][2];   // fully static indexing (loop unrolled)
  f32x4 an[3][2];

  auto ldstep = [&](f32x4 (&dst)[2], int t, int s) {
    long row = (long)t * 128 + wave * 16 + lr;
    if (row > (long)M - 1) row = M - 1;  // clamp tail
    const float* p = A + row * 256 + s * 32 + lj * 8;
    dst[0] = *(const f32x4*)p;
    dst[1] = *(const f32x4*)(p + 4);
  };

  ldstep(a[0], blockIdx.x, 0);
  ldstep(a[1], blockIdx.x, 1);
  ldstep(a[2], blockIdx.x, 2);
  __syncthreads();  // B resident (one-time drain)

  for (int t = blockIdx.x; t < NT; t += G) {
    f32x4 acc[16] = {};
#pragma unroll
    for (int s = 0; s < 8; ++s) {
      // issue the load 3 K-steps ahead (static dst registers)
      if (s < 5)
        ldstep(a[s + 3], t, s + 3);
      else
        ldstep(an[s - 5], t + G, s - 5);
      // compute with a[s] (compiler inserts precise vmcnt for these regs)
      bf16x8 af;
      af[0] = (__bf16)a[s][0][0];
      af[1] = (__bf16)a[s][0][1];
      af[2] = (__bf16)a[s][0][2];
      af[3] = (__bf16)a[s][0][3];
      af[4] = (__bf16)a[s][1][0];
      af[5] = (__bf16)a[s][1][1];
      af[6] = (__bf16)a[s][1][2];
      af[7] = (__bf16)a[s][1][3];
#pragma unroll
      for (int ni = 0; ni < 16; ++ni) {
        int sl = ni * 16 + lr;
        int pc = (s * 4 + lj) ^ (sl & 7);
        bf16x8 b = __builtin_bit_cast(
            bf16x8, *(const u16x8*)((const char*)Bls + sl * 512 + pc * 16));
        acc[ni] = __builtin_amdgcn_mfma_f32_16x16x32_bf16(af, b, acc[ni],
                                                          0, 0, 0);
      }
    }
    // epilogue: lane -> rows lj*4+r, original cols lr*16..lr*16+15
#pragma unroll
    for (int r = 0; r < 4; ++r) {
      long grow = (long)t * 128 + wave * 16 + lj * 4 + r;
      if (grow >= M) continue;
      bf16x8 lo, hi;
#pragma unroll
      for (int j = 0; j < 8; ++j) {
        lo[j] = (__bf16)(acc[j][r] + bv[j]);
        hi[j] = (__bf16)(acc[8 + j][r] + bv[8 + j]);
      }
      u16* pC = Cv + grow * 256 + lr * 16;
      *(u16x8*)pC = __builtin_bit_cast(u16x8, lo);
      *(u16x8*)(pC + 8) = __builtin_bit_cast(u16x8, hi);
    }
    // rotate next-tile prefetch into place (register moves, static)
#pragma unroll
    for (int q = 0; q < 3; ++q) {
      a[q][0] = an[q][0];
      a[q][1] = an[q][1];
    }
  }
}

// ---------------------------------------------------------------------------
// gemm_p2 (small GEMMs, unchanged from R9): B-resident, 4 waves x 16 rows.
template <int WAVES, int NF, bool OUT_BF16>
__global__ __launch_bounds__(WAVES * 64, 1) void gemm_p2(
    const float* __restrict__ A, const u16* __restrict__ Wt,
    const float* __restrict__ bias, void* __restrict__ Cv,
    int M, int NT, int G) {
  constexpr int N = NF * 16;
  constexpr int TR = WAVES * 16;                  // tile rows
  constexpr int STN = OUT_BF16 ? (NF / 2) : NF;   // stores/lane/tile
  __shared__ __align__(16) u16 Bls[N * 256];      // N*512 B
  __shared__ __align__(16) float Asub[WAVES * 1024];  // WAVES*4 KB
  const int wave = threadIdx.x >> 6;
  const int lane = threadIdx.x & 63;
  const int lr = lane & 15;
  const int lj = lane >> 4;

  constexpr int NI = NF * 8 / WAVES;
#pragma unroll
  for (int g = 0; g < NI; ++g) {
    int inst = wave * NI + g;
    int s2 = inst * 2 + (lane >> 5);
    int pc = lane & 31;
    int jc = pc ^ (s2 & 7);
    int c = (s2 & 15) * NF + (s2 >> 4);
    glds16((const char*)Wt + (size_t)c * 512 + (size_t)jc * 16,
           (char*)Bls + inst * 1024);
  }

  float bv[NF];
#pragma unroll
  for (int ni = 0; ni < NF; ++ni) bv[ni] = bias[lr * NF + ni];

  char* aw = (char*)Asub + wave * 4096;

  auto stageA = [&](int t, int s, int buf) {
#pragma unroll
    for (int i = 0; i < 2; ++i) {
      long row = (long)t * TR + wave * 16 + i * 8 + (lane >> 3);
      if (row > (long)M - 1) row = M - 1;
      int jc = (lane & 7) ^ (lane >> 3);
      glds16((const char*)A + row * 1024 + (size_t)s * 128 + (size_t)jc * 16,
             aw + buf * 2048 + i * 1024);
    }
  };

  stageA(blockIdx.x, 0, 0);
  stageA(blockIdx.x, 1, 1);
  __syncthreads();

  for (int t = blockIdx.x; t < NT; t += G) {
    f32x4 acc[NF] = {};
#pragma unroll
    for (int s = 0; s < 8; ++s) {
      if (s < 2) {
        if constexpr (STN == 8)
          asm volatile("s_waitcnt vmcnt(10)" ::: "memory");
        else
          asm volatile("s_waitcnt vmcnt(18)" ::: "memory");
      } else {
        asm volatile("s_waitcnt vmcnt(2)" ::: "memory");
      }
      const char* ab = aw + (s & 1) * 2048;
      const int sw = lr & 7;
      const int j0 = lj * 2;
      f32x4 a0 = *(const f32x4*)(ab + lr * 128 + ((j0 ^ sw) * 16));
      f32x4 a1 = *(const f32x4*)(ab + lr * 128 + (((j0 + 1) ^ sw) * 16));
      bf16x8 af;
      af[0] = (__bf16)a0[0]; af[1] = (__bf16)a0[1];
      af[2] = (__bf16)a0[2]; af[3] = (__bf16)a0[3];
      af[4] = (__bf16)a1[0]; af[5] = (__bf16)a1[1];
      af[6] = (__bf16)a1[2]; af[7] = (__bf16)a1[3];
#pragma unroll
      for (int ni = 0; ni < NF; ++ni) {
        int sl = ni * 16 + lr;
        int pc = (s * 4 + lj) ^ (sl & 7);
        bf16x8 b = __builtin_bit_cast(
            bf16x8, *(const u16x8*)((const char*)Bls + sl * 512 + pc * 16));
        acc[ni] = __builtin_amdgcn_mfma_f32_16x16x32_bf16(af, b, acc[ni],
                                                          0, 0, 0);
      }
      if (s < 6)
        stageA(t, s + 2, s & 1);
      else if (s == 6)
        stageA(t + G, 0, 0);
      else
        stageA(t + G, 1, 1);
    }
#pragma unroll
    for (int r = 0; r < 4; ++r) {
      long grow = (long)t * TR + wave * 16 + lj * 4 + r;
      if (grow >= M) continue;
      if (OUT_BF16) {
        bf16x8 lo, hi;
#pragma unroll
        for (int j = 0; j < 8; ++j) {
          lo[j] = (__bf16)(acc[j][r] + bv[j]);
          hi[j] = (__bf16)(acc[8 + j][r] + bv[8 + j]);
        }
        u16* pC = (u16*)Cv + grow * N + lr * NF;
        *(u16x8*)pC = __builtin_bit_cast(u16x8, lo);
        *(u16x8*)(pC + 8) = __builtin_bit_cast(u16x8, hi);
      } else {
#pragma unroll
        for (int q = 0; q < NF / 4; ++q) {
          f32x4 v;
#pragma unroll
          for (int j = 0; j < 4; ++j) v[j] = acc[q * 4 + j][r] + bv[q * 4 + j];
          *(f32x4*)((float*)Cv + grow * N + lr * NF + q * 4) = v;
        }
      }
    }
  }
}

// ---------------------------------------------------------------------------
// sample_fused (unchanged from R9): XCD batch affinity + LDS precompute.
__global__ __launch_bounds__(256, 4) void sample_fused(
    const float* __restrict__ Lgo, const float* __restrict__ Lga,
    const float* __restrict__ bbox, const u16* __restrict__ vbf,
    float* __restrict__ outs) {
  const int t = threadIdx.x;
  const int bi = blockIdx.x;
  const int xcd = bi & 7;
  const int j = bi >> 3;            // 0..249
  const int half = (j >= 125) ? 1 : 0;
  const int batch = xcd + 8 * half;
  const int qb = j - 125 * half;    // 0..124
  const int i0 = (batch * 125 + qb) * 8;

  __shared__ __align__(16) float sa[8 * 128];
  __shared__ __align__(16) int4 soff[1024];
  __shared__ __align__(16) float4 sw4[1024];
  __shared__ float sb[32];
  if (t < 32) sb[t] = bbox[(size_t)i0 * 4 + t];
  ((float4*)sa)[t] = ((const float4*)(Lga + (size_t)i0 * 128))[t];
  __syncthreads();
  if (t < 64) {
    int base = (t >> 3) * 128 + (t & 7) * 16;
    float mx = -3.0e38f;
#pragma unroll
    for (int k = 0; k < 16; ++k) mx = fmaxf(mx, sa[base + k]);
    float e[16];
    float s = 0.f;
#pragma unroll
    for (int k = 0; k < 16; ++k) {
      e[k] = __expf(sa[base + k] - mx);
      s += e[k];
    }
    float inv = 1.f / s;
#pragma unroll
    for (int k = 0; k < 16; ++k) sa[base + k] = e[k] * inv;
  }
  __syncthreads();
#pragma unroll
  for (int it = 0; it < 4; ++it) {
    int idx = it * 256 + t;
    int ql = idx >> 7;
    int rest = idx & 127;
    int h = rest >> 4;
    int pt = rest & 15;
    int l = pt >> 2;
    int W = 80 >> l;
    float offx = Lgo[(size_t)(i0 + ql) * 256 + h * 32 + pt * 2];
    float offy = Lgo[(size_t)(i0 + ql) * 256 + h * 32 + pt * 2 + 1];
    float xf = (sb[ql * 4 + 0] + offx * 0.125f * sb[ql * 4 + 2]) * (float)W - 0.5f;
    float yf = (sb[ql * 4 + 1] + offy * 0.125f * sb[ql * 4 + 3]) * (float)W - 0.5f;
    float aw = sa[ql * 128 + h * 16 + pt];
    float x0f = floorf(xf), y0f = floorf(yf);
    float wx = xf - x0f, wy = yf - y0f;
    int x0 = (int)x0f, y0 = (int)y0f;
    int x1 = x0 + 1, y1 = y0 + 1;
    float fx0 = (x0 >= 0 && x0 < W) ? 1.f : 0.f;
    float fx1 = (x1 >= 0 && x1 < W) ? 1.f : 0.f;
    float fy0 = (y0 >= 0 && y0 < W) ? 1.f : 0.f;
    float fy1 = (y1 >= 0 && y1 < W) ? 1.f : 0.f;
    int xc0 = min(max(x0, 0), W - 1), xc1 = min(max(x1, 0), W - 1);
    int yc0 = min(max(y0, 0), W - 1), yc1 = min(max(y1, 0), W - 1);
    int baseb = ((25600 - (25600 >> (2 * l))) / 3) * 512;  // bytes
    int4 o;
    o.x = baseb + (yc0 * W + xc0) * 512;
    o.y = baseb + (yc0 * W + xc1) * 512;
    o.z = baseb + (yc1 * W + xc0) * 512;
    o.w = baseb + (yc1 * W + xc1) * 512;
    float aw0 = aw * (1.f - wy), aw1 = aw * wy;
    float4 wv;
    wv.x = aw0 * (1.f - wx) * fx0 * fy0;
    wv.y = aw0 * wx * fx1 * fy0;
    wv.z = aw1 * (1.f - wx) * fx0 * fy1;
    wv.w = aw1 * wx * fx1 * fy1;
    int phys = ql * 128 + h * 16 + (pt ^ h);
    soff[phys] = o;
    sw4[phys] = wv;
  }
  __syncthreads();
  const int ql = t >> 5;
  const int r = t & 31;
  const int h = r >> 2;
  const int cg = r & 3;
  const int chb = (h * 32 + cg * 8) * 2;
  const char* vbb = (const char*)vbf + (size_t)batch * 8500 * 512 + chb;
  float acc[8] = {};
#pragma unroll 2
  for (int pt = 0; pt < 16; ++pt) {
    int phys = ql * 128 + h * 16 + (pt ^ h);
    int4 o = soff[phys];
    float4 wv = sw4[phys];
    uint4 v00 = *(const uint4*)(vbb + o.x);
    uint4 v01 = *(const uint4*)(vbb + o.y);
    uint4 v10 = *(const uint4*)(vbb + o.z);
    uint4 v11 = *(const uint4*)(vbb + o.w);
    const uint32_t* p00 = (const uint32_t*)&v00;
    const uint32_t* p01 = (const uint32_t*)&v01;
    const uint32_t* p10 = (const uint32_t*)&v10;
    const uint32_t* p11 = (const uint32_t*)&v11;
#pragma unroll
    for (int k = 0; k < 4; ++k) {
      float a0 = __uint_as_float(p00[k] << 16);
      float a1 = __uint_as_float(p00[k] & 0xffff0000u);
      float b0 = __uint_as_float(p01[k] << 16);
      float b1 = __uint_as_float(p01[k] & 0xffff0000u);
      float c0 = __uint_as_float(p10[k] << 16);
      float c1 = __uint_as_float(p10[k] & 0xffff0000u);
      float d0 = __uint_as_float(p11[k] << 16);
      float d1 = __uint_as_float(p11[k] & 0xffff0000u);
      acc[2 * k] += wv.x * a0 + wv.y * b0 + wv.z * c0 + wv.w * d0;
      acc[2 * k + 1] += wv.x * a1 + wv.y * b1 + wv.z * c1 + wv.w * d1;
    }
  }
  float4* op = (float4*)(outs + (size_t)(i0 + ql) * 256 + h * 32 + cg * 8);
  op[0] = make_float4(acc[0], acc[1], acc[2], acc[3]);
  op[1] = make_float4(acc[4], acc[5], acc[6], acc[7]);
}

extern "C" void kernel_launch(void* const* d_in, const int* in_sizes, int n_in,
                              void* d_out, int out_size, void* d_ws, size_t ws_size,
                              hipStream_t stream) {
  const float* query  = (const float*)d_in[0];
  const float* bbox   = (const float*)d_in[1];
  const float* value  = (const float*)d_in[2];
  const float* W_off  = (const float*)d_in[3];
  const float* b_off  = (const float*)d_in[4];
  const float* W_attn = (const float*)d_in[5];
  const float* b_attn = (const float*)d_in[6];
  const float* W_val  = (const float*)d_in[7];
  const float* b_val  = (const float*)d_in[8];
  const float* W_out  = (const float*)d_in[9];
  const float* b_out  = (const float*)d_in[10];
  float* out = (float*)d_out;

  // workspace layout
  char* w = (char*)d_ws;
  u16* vbf     = (u16*)w;                    // 69,632,000 B
  float* Lgo   = (float*)(w + 69632000);     // 16,384,000 B
  float* Lga   = (float*)(w + 86016000);     //  8,192,000 B
  float* outs  = (float*)(w + 94208000);     // 16,384,000 B
  u16* Wt_val  = (u16*)(w + 110592000);      //    131,072 B
  u16* Wt_off  = (u16*)(w + 110723072);      //    131,072 B
  u16* Wt_attn = (u16*)(w + 110854144);      //     65,536 B
  u16* Wt_out  = (u16*)(w + 110919680);      //    131,072 B

  const int M_v = 16 * 8500;  // 136000
  const int M_q = 16 * 1000;  // 16000

  // 0) weight prep (bf16 transpose)
  wconv<<<dim3(4, 4, 4), 256, 0, stream>>>(W_val, W_off, W_attn, W_out,
                                           Wt_val, Wt_off, Wt_attn, Wt_out);
  // 1) value projection -> bf16 (persistent, register-pipelined A)
  gemm_v4<<<256, 512, 0, stream>>>(value, Wt_val, b_val, vbf, M_v, 1063, 256);
  // 2) offset logits [16000x256]
  gemm_p2<4, 16, false><<<250, 256, 0, stream>>>(
      query, Wt_off, b_off, (void*)Lgo, M_q, 250, 250);
  // 3) attn logits [16000x128]
  gemm_p2<4, 8, false><<<250, 256, 0, stream>>>(
      query, Wt_attn, b_attn, (void*)Lga, M_q, 250, 250);
  // 4) fused softmax/locs + bilinear sampling (XCD batch affinity)
  sample_fused<<<2000, 256, 0, stream>>>(Lgo, Lga, bbox, vbf, outs);
  // 5) output projection
  gemm_p2<4, 16, false><<<250, 256, 0, stream>>>(
      outs, Wt_out, b_out, (void*)out, M_q, 250, 250);
}

// Round 14
// 124.370 us; speedup vs baseline: 3.1233x; 3.1233x over previous
//
#include <hip/hip_runtime.h>
#include <cstdint>
#include <cstddef>

// DeformablePoseViT: bs=16, lq=1000, d=256, nh=8, L=4, P=4, dh=32
// value pyramid: (80,80),(40,40),(20,20),(10,10) -> lv=8500
//
// Pipeline (R9 structure — best measured: 124.7us):
//  0) wconv : Wt_* = bf16(W_*^T) [N][256] for the 4 weight matrices
//  1) gemm_p2<8,16,true> : vbf = bf16(value @ W_val + b_val) [136000x256]
//  2) gemm_p2<4,16,false>: Lgo = query @ W_off + b_off       [16000x256]
//  3) gemm_p2<4,8,false> : Lga = query @ W_attn + b_attn     [16000x128]
//  4) sample_fused : softmax + weight/offset precompute (LDS) + gather
//  5) gemm_p2<4,16,false>: d_out = outs @ W_out + b_out      [16000x256]
//
// gemm_p2: persistent B-resident GEMM, WAVES waves x 16 rows/wave.
// B (N x 256 bf16) resident in LDS, col-permuted (slot ni*16+lr <-> orig col
// lr*NF+ni -> contiguous per-lane C stores) + 16B-chunk XOR swizzle.
// A staged per-wave-private via global_load_lds 2x2KB ping-pong, counted
// in-order vmcnt schedule (next-tile chunks staged BEFORE epilogue stores so
// s<2 waits need not drain stores). No cross-wave barriers after init.
// NOTE (R10-R12 lessons): deeper pipelining fails — reg-resident A spills
// (compiler caps ~128 VGPR on 512-thr), LDS depth capped by B=128KB, and
// atomic work-stealing forces vmcnt(0) per unit. This config is the optimum.

typedef unsigned short u16;
typedef u16 u16x8 __attribute__((ext_vector_type(8)));
typedef __bf16 bf16x8 __attribute__((ext_vector_type(8)));
typedef float f32x4 __attribute__((ext_vector_type(4)));

__device__ inline u16 f2bf(float f) {
  return __builtin_bit_cast(u16, (__bf16)f);
}

__device__ __forceinline__ void glds16(const void* g, void* l) {
  __builtin_amdgcn_global_load_lds(
      (const __attribute__((address_space(1))) void*)g,
      (__attribute__((address_space(3))) void*)l, 16, 0, 0);
}

// ---------------------------------------------------------------------------
// Weight prep: Wt[n][k] = bf16(W[k][n]). K=256 for all 4 matrices.
__global__ __launch_bounds__(256) void wconv(
    const float* __restrict__ W0, const float* __restrict__ W1,
    const float* __restrict__ W2, const float* __restrict__ W3,
    u16* __restrict__ T0, u16* __restrict__ T1, u16* __restrict__ T2,
    u16* __restrict__ T3) {
  __shared__ u16 tile[64][65];
  const float* Ws[4] = {W0, W1, W2, W3};
  u16* Ts[4] = {T0, T1, T2, T3};
  const int Ns[4] = {256, 256, 128, 256};
  const int z = blockIdx.z;
  const int N = Ns[z];
  const int n0 = blockIdx.x * 64;
  if (n0 >= N) return;
  const int k0 = blockIdx.y * 64;
  const float* W = Ws[z];
  u16* Wt = Ts[z];
  const int tr = threadIdx.x >> 6;   // 0..3
  const int tc = threadIdx.x & 63;
#pragma unroll
  for (int r = 0; r < 64; r += 4)
    tile[r + tr][tc] = f2bf(W[(size_t)(k0 + r + tr) * N + n0 + tc]);
  __syncthreads();
#pragma unroll
  for (int r = 0; r < 64; r += 4)
    Wt[(size_t)(n0 + r + tr) * 256 + k0 + tc] = tile[tc][r + tr];
}

// ---------------------------------------------------------------------------
// C[M,N] = A[M,256]f32 (cast bf16) @ Wt[N,256]bf16^T + bias[N]
template <int WAVES, int NF, bool OUT_BF16>
__global__ __launch_bounds__(WAVES * 64, 1) void gemm_p2(
    const float* __restrict__ A, const u16* __restrict__ Wt,
    const float* __restrict__ bias, void* __restrict__ Cv,
    int M, int NT, int G) {
  constexpr int N = NF * 16;
  constexpr int TR = WAVES * 16;                  // tile rows
  constexpr int STN = OUT_BF16 ? (NF / 2) : NF;   // stores/lane/tile
  __shared__ __align__(16) u16 Bls[N * 256];      // N*512 B
  __shared__ __align__(16) float Asub[WAVES * 1024];  // WAVES*4 KB
  const int wave = threadIdx.x >> 6;
  const int lane = threadIdx.x & 63;
  const int lr = lane & 15;
  const int lj = lane >> 4;

  // ---- B preload (once per block): NF*8 insts of 1KB (2 permuted cols) ----
  constexpr int NI = NF * 8 / WAVES;
#pragma unroll
  for (int g = 0; g < NI; ++g) {
    int inst = wave * NI + g;
    int s2 = inst * 2 + (lane >> 5);
    int pc = lane & 31;
    int jc = pc ^ (s2 & 7);
    int c = (s2 & 15) * NF + (s2 >> 4);  // original column for slot s2
    glds16((const char*)Wt + (size_t)c * 512 + (size_t)jc * 16,
           (char*)Bls + inst * 1024);
  }

  float bv[NF];
#pragma unroll
  for (int ni = 0; ni < NF; ++ni) bv[ni] = bias[lr * NF + ni];

  char* aw = (char*)Asub + wave * 4096;

  auto stageA = [&](int t, int s, int buf) {
#pragma unroll
    for (int i = 0; i < 2; ++i) {
      long row = (long)t * TR + wave * 16 + i * 8 + (lane >> 3);
      if (row > (long)M - 1) row = M - 1;  // clamp (no predication on glds)
      int jc = (lane & 7) ^ (lane >> 3);
      glds16((const char*)A + row * 1024 + (size_t)s * 128 + (size_t)jc * 16,
             aw + buf * 2048 + i * 1024);
    }
  };

  stageA(blockIdx.x, 0, 0);
  stageA(blockIdx.x, 1, 1);
  __syncthreads();  // one-time full drain: B + first A chunks resident

  for (int t = blockIdx.x; t < NT; t += G) {
    f32x4 acc[NF] = {};
#pragma unroll
    for (int s = 0; s < 8; ++s) {
      // in-order FIFO per wave: [c_s(2), c_{s+1}(2), (stores at s<2)]
      if (s < 2) {
        if constexpr (STN == 8)
          asm volatile("s_waitcnt vmcnt(10)" ::: "memory");
        else
          asm volatile("s_waitcnt vmcnt(18)" ::: "memory");
      } else {
        asm volatile("s_waitcnt vmcnt(2)" ::: "memory");
      }
      const char* ab = aw + (s & 1) * 2048;
      // A fragment: row lr, k-chunk pair lj*2, lj*2+1 (XOR by row&7)
      const int sw = lr & 7;
      const int j0 = lj * 2;
      f32x4 a0 = *(const f32x4*)(ab + lr * 128 + ((j0 ^ sw) * 16));
      f32x4 a1 = *(const f32x4*)(ab + lr * 128 + (((j0 + 1) ^ sw) * 16));
      bf16x8 af;
      af[0] = (__bf16)a0[0]; af[1] = (__bf16)a0[1];
      af[2] = (__bf16)a0[2]; af[3] = (__bf16)a0[3];
      af[4] = (__bf16)a1[0]; af[5] = (__bf16)a1[1];
      af[6] = (__bf16)a1[2]; af[7] = (__bf16)a1[3];
#pragma unroll
      for (int ni = 0; ni < NF; ++ni) {
        int sl = ni * 16 + lr;
        int pc = (s * 4 + lj) ^ (sl & 7);
        bf16x8 b = __builtin_bit_cast(
            bf16x8, *(const u16x8*)((const char*)Bls + sl * 512 + pc * 16));
        acc[ni] = __builtin_amdgcn_mfma_f32_16x16x32_bf16(af, b, acc[ni],
                                                          0, 0, 0);
      }
      if (s < 6)
        stageA(t, s + 2, s & 1);
      else if (s == 6)
        stageA(t + G, 0, 0);  // next tile chunk 0 (before epilogue stores)
      else
        stageA(t + G, 1, 1);  // next tile chunk 1
    }
    // epilogue: lane writes rows wave*16+lj*4+r, cols lr*NF..lr*NF+NF-1
#pragma unroll
    for (int r = 0; r < 4; ++r) {
      long grow = (long)t * TR + wave * 16 + lj * 4 + r;
      if (grow >= M) continue;
      if (OUT_BF16) {
        bf16x8 lo, hi;
#pragma unroll
        for (int j = 0; j < 8; ++j) {
          lo[j] = (__bf16)(acc[j][r] + bv[j]);
          hi[j] = (__bf16)(acc[8 + j][r] + bv[8 + j]);
        }
        u16* pC = (u16*)Cv + grow * N + lr * NF;
        *(u16x8*)pC = __builtin_bit_cast(u16x8, lo);
        *(u16x8*)(pC + 8) = __builtin_bit_cast(u16x8, hi);
      } else {
#pragma unroll
        for (int q = 0; q < NF / 4; ++q) {
          f32x4 v;
#pragma unroll
          for (int j = 0; j < 4; ++j) v[j] = acc[q * 4 + j][r] + bv[q * 4 + j];
          *(f32x4*)((float*)Cv + grow * N + lr * NF + q * 4) = v;
        }
      }
    }
  }
}

// ---------------------------------------------------------------------------
// sample_fused: XCD batch affinity + LDS weight/offset precompute.
__global__ __launch_bounds__(256, 4) void sample_fused(
    const float* __restrict__ Lgo, const float* __restrict__ Lga,
    const float* __restrict__ bbox, const u16* __restrict__ vbf,
    float* __restrict__ outs) {
  const int t = threadIdx.x;
  const int bi = blockIdx.x;
  const int xcd = bi & 7;
  const int j = bi >> 3;            // 0..249
  const int half = (j >= 125) ? 1 : 0;
  const int batch = xcd + 8 * half;
  const int qb = j - 125 * half;    // 0..124
  const int i0 = (batch * 125 + qb) * 8;

  __shared__ __align__(16) float sa[8 * 128];
  __shared__ __align__(16) int4 soff[1024];
  __shared__ __align__(16) float4 sw4[1024];
  __shared__ float sb[32];
  if (t < 32) sb[t] = bbox[(size_t)i0 * 4 + t];
  ((float4*)sa)[t] = ((const float4*)(Lga + (size_t)i0 * 128))[t];
  __syncthreads();
  if (t < 64) {
    int base = (t >> 3) * 128 + (t & 7) * 16;
    float mx = -3.0e38f;
#pragma unroll
    for (int k = 0; k < 16; ++k) mx = fmaxf(mx, sa[base + k]);
    float e[16];
    float s = 0.f;
#pragma unroll
    for (int k = 0; k < 16; ++k) {
      e[k] = __expf(sa[base + k] - mx);
      s += e[k];
    }
    float inv = 1.f / s;
#pragma unroll
    for (int k = 0; k < 16; ++k) sa[base + k] = e[k] * inv;
  }
  __syncthreads();
#pragma unroll
  for (int it = 0; it < 4; ++it) {
    int idx = it * 256 + t;
    int ql = idx >> 7;
    int rest = idx & 127;
    int h = rest >> 4;
    int pt = rest & 15;
    int l = pt >> 2;
    int W = 80 >> l;
    float2 off2 = *(const float2*)(Lgo + (size_t)(i0 + ql) * 256 + h * 32 + pt * 2);
    float xf = (sb[ql * 4 + 0] + off2.x * 0.125f * sb[ql * 4 + 2]) * (float)W - 0.5f;
    float yf = (sb[ql * 4 + 1] + off2.y * 0.125f * sb[ql * 4 + 3]) * (float)W - 0.5f;
    float aw = sa[ql * 128 + h * 16 + pt];
    float x0f = floorf(xf), y0f = floorf(yf);
    float wx = xf - x0f, wy = yf - y0f;
    int x0 = (int)x0f, y0 = (int)y0f;
    int x1 = x0 + 1, y1 = y0 + 1;
    float fx0 = (x0 >= 0 && x0 < W) ? 1.f : 0.f;
    float fx1 = (x1 >= 0 && x1 < W) ? 1.f : 0.f;
    float fy0 = (y0 >= 0 && y0 < W) ? 1.f : 0.f;
    float fy1 = (y1 >= 0 && y1 < W) ? 1.f : 0.f;
    int xc0 = min(max(x0, 0), W - 1), xc1 = min(max(x1, 0), W - 1);
    int yc0 = min(max(y0, 0), W - 1), yc1 = min(max(y1, 0), W - 1);
    int baseb = ((25600 - (25600 >> (2 * l))) / 3) * 512;  // bytes
    int4 o;
    o.x = baseb + (yc0 * W + xc0) * 512;
    o.y = baseb + (yc0 * W + xc1) * 512;
    o.z = baseb + (yc1 * W + xc0) * 512;
    o.w = baseb + (yc1 * W + xc1) * 512;
    float aw0 = aw * (1.f - wy), aw1 = aw * wy;
    float4 wv;
    wv.x = aw0 * (1.f - wx) * fx0 * fy0;
    wv.y = aw0 * wx * fx1 * fy0;
    wv.z = aw1 * (1.f - wx) * fx0 * fy1;
    wv.w = aw1 * wx * fx1 * fy1;
    int phys = ql * 128 + h * 16 + (pt ^ h);
    soff[phys] = o;
    sw4[phys] = wv;
  }
  __syncthreads();
  const int ql = t >> 5;
  const int r = t & 31;
  const int h = r >> 2;
  const int cg = r & 3;
  const int chb = (h * 32 + cg * 8) * 2;
  const char* vbb = (const char*)vbf + (size_t)batch * 8500 * 512 + chb;
  float acc[8] = {};
#pragma unroll 2
  for (int pt = 0; pt < 16; ++pt) {
    int phys = ql * 128 + h * 16 + (pt ^ h);
    int4 o = soff[phys];
    float4 wv = sw4[phys];
    uint4 v00 = *(const uint4*)(vbb + o.x);
    uint4 v01 = *(const uint4*)(vbb + o.y);
    uint4 v10 = *(const uint4*)(vbb + o.z);
    uint4 v11 = *(const uint4*)(vbb + o.w);
    const uint32_t* p00 = (const uint32_t*)&v00;
    const uint32_t* p01 = (const uint32_t*)&v01;
    const uint32_t* p10 = (const uint32_t*)&v10;
    const uint32_t* p11 = (const uint32_t*)&v11;
#pragma unroll
    for (int k = 0; k < 4; ++k) {
      float a0 = __uint_as_float(p00[k] << 16);
      float a1 = __uint_as_float(p00[k] & 0xffff0000u);
      float b0 = __uint_as_float(p01[k] << 16);
      float b1 = __uint_as_float(p01[k] & 0xffff0000u);
      float c0 = __uint_as_float(p10[k] << 16);
      float c1 = __uint_as_float(p10[k] & 0xffff0000u);
      float d0 = __uint_as_float(p11[k] << 16);
      float d1 = __uint_as_float(p11[k] & 0xffff0000u);
      acc[2 * k] += wv.x * a0 + wv.y * b0 + wv.z * c0 + wv.w * d0;
      acc[2 * k + 1] += wv.x * a1 + wv.y * b1 + wv.z * c1 + wv.w * d1;
    }
  }
  float4* op = (float4*)(outs + (size_t)(i0 + ql) * 256 + h * 32 + cg * 8);
  op[0] = make_float4(acc[0], acc[1], acc[2], acc[3]);
  op[1] = make_float4(acc[4], acc[5], acc[6], acc[7]);
}

extern "C" void kernel_launch(void* const* d_in, const int* in_sizes, int n_in,
                              void* d_out, int out_size, void* d_ws, size_t ws_size,
                              hipStream_t stream) {
  const float* query  = (const float*)d_in[0];
  const float* bbox   = (const float*)d_in[1];
  const float* value  = (const float*)d_in[2];
  const float* W_off  = (const float*)d_in[3];
  const float* b_off  = (const float*)d_in[4];
  const float* W_attn = (const float*)d_in[5];
  const float* b_attn = (const float*)d_in[6];
  const float* W_val  = (const float*)d_in[7];
  const float* b_val  = (const float*)d_in[8];
  const float* W_out  = (const float*)d_in[9];
  const float* b_out  = (const float*)d_in[10];
  float* out = (float*)d_out;

  // workspace layout
  char* w = (char*)d_ws;
  u16* vbf     = (u16*)w;                    // 69,632,000 B
  float* Lgo   = (float*)(w + 69632000);     // 16,384,000 B
  float* Lga   = (float*)(w + 86016000);     //  8,192,000 B
  float* outs  = (float*)(w + 94208000);     // 16,384,000 B
  u16* Wt_val  = (u16*)(w + 110592000);      //    131,072 B
  u16* Wt_off  = (u16*)(w + 110723072);      //    131,072 B
  u16* Wt_attn = (u16*)(w + 110854144);      //     65,536 B
  u16* Wt_out  = (u16*)(w + 110919680);      //    131,072 B

  const int M_v = 16 * 8500;  // 136000
  const int M_q = 16 * 1000;  // 16000

  // 0) weight prep (bf16 transpose)
  wconv<<<dim3(4, 4, 4), 256, 0, stream>>>(W_val, W_off, W_attn, W_out,
                                           Wt_val, Wt_off, Wt_attn, Wt_out);
  // 1) value projection -> bf16 (persistent, 512 thr, 8 waves, 160KB LDS)
  gemm_p2<8, 16, true><<<256, 512, 0, stream>>>(
      value, Wt_val, b_val, (void*)vbf, M_v, 1063, 256);
  // 2) offset logits [16000x256]: 250 blocks x 64-row tiles
  gemm_p2<4, 16, false><<<250, 256, 0, stream>>>(
      query, Wt_off, b_off, (void*)Lgo, M_q, 250, 250);
  // 3) attn logits [16000x128]
  gemm_p2<4, 8, false><<<250, 256, 0, stream>>>(
      query, Wt_attn, b_attn, (void*)Lga, M_q, 250, 250);
  // 4) fused softmax/locs + bilinear sampling (XCD batch affinity)
  sample_fused<<<2000, 256, 0, stream>>>(Lgo, Lga, bbox, vbf, outs);
  // 5) output projection
  gemm_p2<4, 16, false><<<250, 256, 0, stream>>>(
      outs, Wt_out, b_out, (void*)out, M_q, 250, 250);
}